// Round 3
// baseline (489.712 us; speedup 1.0000x reference)
//
#include <hip/hip_runtime.h>
#include <math.h>

#define BATCH 48
#define HH 128
#define WW 128
#define HW (128*128)
#define SZ (48*16*HW)          // 12,582,912 floats per 16-ch feature map
#define EPS 1e-5f

// mish(x) = x*tanh(softplus(x)) = x * t(t+2)/(t(t+2)+2), t = e^x  (exact identity)
__device__ __forceinline__ float mishf(float v) {
    float t = __expf(fminf(v, 20.f));      // clamp: for v>20 result == v to fp32 precision
    float u = t * (t + 2.f);
    return v * (u / (u + 2.f));
}

// XCD-affinity decode: linear block L -> (xcd = L&7) owns batches b == xcd (mod 8).
// bpb = blocks per batch (must divide gridDim/8 evenly; grids sized so it does).
__device__ __forceinline__ void xcd_decode(int L, int bpb, int& b, int& w) {
    int xcd = L & 7;
    int j   = L >> 3;
    b = xcd + 8 * (j / bpb);
    w = j - (j / bpb) * bpb;
}

// ---------------- K1: 1x1 conv 32->16 (high_fea -> in0) + weight transposes ----------------
// grid 768 = 48 b * 16 blocks; XCD-sharded by batch.
__global__ __launch_bounds__(256) void k_c0(const float* __restrict__ x,
                                            const float* __restrict__ W,
                                            const float* __restrict__ Wc1,
                                            const float* __restrict__ Wc2,
                                            const float* __restrict__ Wref,
                                            float* __restrict__ WTb,   // 1152 floats
                                            float* __restrict__ WTr,   // 2304 floats
                                            float* __restrict__ out) {
    __shared__ float w[16*32];
    int tid = threadIdx.x;
    for (int i = tid; i < 512; i += 256) w[i] = W[i];
    if (blockIdx.x == 0) {
        for (int i = tid; i < 576; i += 256) {
            int co = i & 7; int t = i >> 3; int kyx = t % 9; int ci = t / 9;
            WTb[(ci*9 + kyx)*8 + co]       = Wc1[(co*8 + ci)*9 + kyx];
            WTb[576 + (ci*9 + kyx)*8 + co] = Wc2[(co*8 + ci)*9 + kyx];
        }
        for (int i = tid; i < 2304; i += 256) {
            int co = i & 7; int t = i >> 3; int kyx = t % 9; int cih = t / 9;  // 0..31
            int ci = cih & 15; int h = cih >> 4;
            WTr[((h*16 + ci)*9 + kyx)*8 + co] = Wref[((h*8 + co)*16 + ci)*9 + kyx];
        }
    }
    __syncthreads();
    int b, wblk;
    xcd_decode(blockIdx.x, 16, b, wblk);
    int off = ((wblk*256 + tid) << 2);       // 1024 px per block, 16 blocks per batch
    const float* xb = x + (size_t)b * 32 * HW + off;
    float acc[16][4];
    #pragma unroll
    for (int c = 0; c < 16; ++c) { acc[c][0]=acc[c][1]=acc[c][2]=acc[c][3]=0.f; }
    #pragma unroll 4
    for (int ci = 0; ci < 32; ++ci) {
        float4 xv = *(const float4*)(xb + (size_t)ci * HW);
        #pragma unroll
        for (int co = 0; co < 16; ++co) {
            float wv = w[co*32 + ci];
            acc[co][0] += wv*xv.x; acc[co][1] += wv*xv.y;
            acc[co][2] += wv*xv.z; acc[co][3] += wv*xv.w;
        }
    }
    float* ob = out + (size_t)b * 16 * HW + off;
    #pragma unroll
    for (int co = 0; co < 16; ++co)
        *(float4*)(ob + (size_t)co * HW) = make_float4(acc[co][0],acc[co][1],acc[co][2],acc[co][3]);
}

// ---------------- direct-from-global 3x3 conv body (no LDS, no barriers) ----------------
template<int D, int NCI>
__device__ __forceinline__ void dconv_body(const float* __restrict__ base,   // input, NCI ch planes
                                           const float* __restrict__ wb,    // NCI*72 floats [ci][kyx][co8]
                                           const float* __restrict__ zb,    // >=16 zeroed floats
                                           float* __restrict__ obase,       // output, 8 ch planes
                                           float* __restrict__ statp,       // 2 floats (sum, sumsq)
                                           int x0, int y0, int tid) {
    int tx = tid & 15, ty = tid >> 4;
    int y  = y0 + ty;
    int xg = x0 + tx*4 - 4;                 // leftmost float of the 12-float window (mult of 4)
    bool mx0 = (xg >= 0);                   // f4 @ xg
    bool mx2 = (xg + 11 < 128);             // f4 @ xg+8

    float acc[8][4];
    #pragma unroll
    for (int c = 0; c < 8; ++c) { acc[c][0]=acc[c][1]=acc[c][2]=acc[c][3]=0.f; }

    #pragma unroll 2
    for (int ci = 0; ci < NCI; ++ci) {
        const float* cb = base + (size_t)ci * HW + xg;
        #pragma unroll
        for (int ky = 0; ky < 3; ++ky) {
            int gy = y + D*(ky-1);
            bool myv = (unsigned)gy < 128u;
            const float* rp = cb + gy*WW;
            float4 a  = *(const float4*)((myv && mx0) ? rp     : zb);
            float4 bq = *(const float4*)( myv         ? rp + 4 : zb);
            float4 cq = *(const float4*)((myv && mx2) ? rp + 8 : zb);
            float u[12] = {a.x,a.y,a.z,a.w, bq.x,bq.y,bq.z,bq.w, cq.x,cq.y,cq.z,cq.w};
            #pragma unroll
            for (int kx = 0; kx < 3; ++kx) {
                const float* wp = wb + (ci*9 + ky*3 + kx) * 8;
                float w0 = wp[0], w1 = wp[1], w2 = wp[2], w3 = wp[3];
                float w4 = wp[4], w5 = wp[5], w6 = wp[6], w7 = wp[7];
                #pragma unroll
                for (int j = 0; j < 4; ++j) {
                    float xv = u[4 - D + D*kx + j];
                    acc[0][j] += w0*xv; acc[1][j] += w1*xv;
                    acc[2][j] += w2*xv; acc[3][j] += w3*xv;
                    acc[4][j] += w4*xv; acc[5][j] += w5*xv;
                    acc[6][j] += w6*xv; acc[7][j] += w7*xv;
                }
            }
        }
    }

    // ---- write + GN partial stats ----
    float s = 0.f, q = 0.f;
    float* ob = obase + (y0 + ty) * WW + x0 + tx * 4;
    #pragma unroll
    for (int c = 0; c < 8; ++c) {
        *(float4*)(ob + (size_t)c * HW) = make_float4(acc[c][0],acc[c][1],acc[c][2],acc[c][3]);
        #pragma unroll
        for (int j = 0; j < 4; ++j) { s += acc[c][j]; q += acc[c][j]*acc[c][j]; }
    }
    #pragma unroll
    for (int o = 32; o > 0; o >>= 1) { s += __shfl_down(s,o); q += __shfl_down(q,o); }
    if ((tid & 63) == 0) { atomicAdd(&statp[0], s); atomicAdd(&statp[1], q); }
}

// ---------------- K2: dual-branch 3x3, direct conv; flat grid 1536, XCD-sharded ----------------
// per batch: 32 blocks = 2 branch * 8 yblk * 2 xblk
__global__ __launch_bounds__(256) void k_branch3(const float* __restrict__ in0,
                                                 const float* __restrict__ WTb,
                                                 const float* __restrict__ zb,
                                                 float* __restrict__ outp,
                                                 float* __restrict__ stat) {
    int b, w;
    xcd_decode(blockIdx.x, 32, b, w);
    int br = w >> 4;
    int y0 = ((w >> 1) & 7) << 4;
    int x0 = (w & 1) << 6;
    int tid = threadIdx.x;
    if (br == 0) {
        dconv_body<1,8>(in0 + (size_t)(b*16    )*HW, WTb,       zb,
                        outp + (size_t)(b*16    )*HW, stat + b*2, x0, y0, tid);
    } else {
        dconv_body<2,8>(in0 + (size_t)(b*16 + 8)*HW, WTb + 576, zb,
                        outp + (size_t)(b*16 + 8)*HW, stat + b*2, x0, y0, tid);
    }
}

// ---------------- K3: 1x1 conv 24->16 (low) + GN(groups=2) stats; XCD-sharded ----------------
__global__ __launch_bounds__(256) void k_low(const float* __restrict__ x,
                                             const float* __restrict__ W,
                                             float* __restrict__ outp,
                                             float* __restrict__ stat) {
    __shared__ float w[16*24];
    int tid = threadIdx.x;
    for (int i = tid; i < 384; i += 256) w[i] = W[i];
    __syncthreads();
    int b, wblk;
    xcd_decode(blockIdx.x, 16, b, wblk);
    int off = ((wblk*256 + tid) << 2);
    const float* xb = x + (size_t)b * 24 * HW + off;
    float acc[16][4];
    #pragma unroll
    for (int c = 0; c < 16; ++c) { acc[c][0]=acc[c][1]=acc[c][2]=acc[c][3]=0.f; }
    #pragma unroll 4
    for (int ci = 0; ci < 24; ++ci) {
        float4 xv = *(const float4*)(xb + (size_t)ci * HW);
        #pragma unroll
        for (int co = 0; co < 16; ++co) {
            float wv = w[co*24 + ci];
            acc[co][0] += wv*xv.x; acc[co][1] += wv*xv.y;
            acc[co][2] += wv*xv.z; acc[co][3] += wv*xv.w;
        }
    }
    float* ob = outp + (size_t)b * 16 * HW + off;
    float s0=0.f,q0=0.f,s1=0.f,q1=0.f;
    #pragma unroll
    for (int co = 0; co < 16; ++co) {
        *(float4*)(ob + (size_t)co * HW) = make_float4(acc[co][0],acc[co][1],acc[co][2],acc[co][3]);
        #pragma unroll
        for (int j = 0; j < 4; ++j) {
            if (co < 8) { s0 += acc[co][j]; q0 += acc[co][j]*acc[co][j]; }
            else        { s1 += acc[co][j]; q1 += acc[co][j]*acc[co][j]; }
        }
    }
    #pragma unroll
    for (int o = 32; o > 0; o >>= 1) {
        s0 += __shfl_down(s0,o); q0 += __shfl_down(q0,o);
        s1 += __shfl_down(s1,o); q1 += __shfl_down(q1,o);
    }
    if ((tid & 63) == 0) {
        atomicAdd(&stat[b*4+0], s0); atomicAdd(&stat[b*4+1], q0);
        atomicAdd(&stat[b*4+2], s1); atomicAdd(&stat[b*4+3], q1);
    }
}

// ---------------- K4: GN-apply (high & low) + add + mish; XCD-sharded ----------------
// grid 12288 = 48 b * 256 blocks (each 1024 floats of the 262144-float batch slab)
__global__ __launch_bounds__(256) void k_fuse(const float* __restrict__ hp, const float* __restrict__ lp,
                                              const float* __restrict__ gbn, const float* __restrict__ bbn,
                                              const float* __restrict__ glow, const float* __restrict__ blow,
                                              const float* __restrict__ sh, const float* __restrict__ sl,
                                              float* __restrict__ r) {
    int b, wblk;
    xcd_decode(blockIdx.x, 256, b, wblk);
    int idx = wblk*256 + threadIdx.x;        // 0..65535 f4-groups within batch
    int p = b*262144 + (idx << 2);
    int c = idx >> 12;                       // channel 0..15
    float muh = sh[b*2] * (1.f/262144.f);
    float varh = sh[b*2+1]*(1.f/262144.f) - muh*muh;
    float rsh = rsqrtf(varh + EPS);
    int gi = b*4 + (c>>3)*2;
    float mul = sl[gi] * (1.f/131072.f);
    float varl = sl[gi+1]*(1.f/131072.f) - mul*mul;
    float rsl = rsqrtf(varl + EPS);
    float ga = gbn[c]*rsh, bh = bbn[c] - muh*ga;
    float gl = glow[c]*rsl, bl = blow[c] - mul*gl;
    float4 h = *(const float4*)(hp + (size_t)p);
    float4 l = *(const float4*)(lp + (size_t)p);
    float4 o;
    o.x = mishf(h.x*ga + bh + l.x*gl + bl);
    o.y = mishf(h.y*ga + bh + l.y*gl + bl);
    o.z = mishf(h.z*ga + bh + l.z*gl + bl);
    o.w = mishf(h.w*ga + bh + l.w*gl + bl);
    *(float4*)(r + (size_t)p) = o;
}

// ---------------- K5: 3x3 conv 16->16 pad1, direct conv; flat grid 1536, XCD-sharded ----------------
// per batch: 32 blocks = 2 co-half * 8 yblk * 2 xblk
__global__ __launch_bounds__(256) void k_ref3(const float* __restrict__ rin,
                                              const float* __restrict__ WTr,
                                              const float* __restrict__ zb,
                                              float* __restrict__ outp,
                                              float* __restrict__ stat) {
    int b, w;
    xcd_decode(blockIdx.x, 32, b, w);
    int h  = w >> 4;
    int y0 = ((w >> 1) & 7) << 4;
    int x0 = (w & 1) << 6;
    int tid = threadIdx.x;
    dconv_body<1,16>(rin + (size_t)b*16*HW, WTr + h*1152, zb,
                     outp + (size_t)(b*16 + h*8)*HW, stat + b*4 + h*2, x0, y0, tid);
}

// ---------------- K6: GN-apply + mish + 1x1 seg conv 16->1; XCD-sharded ----------------
__global__ __launch_bounds__(256) void k_seg(const float* __restrict__ rp,
                                             const float* __restrict__ gref, const float* __restrict__ bref,
                                             const float* __restrict__ wseg, const float* __restrict__ sr,
                                             float* __restrict__ seg) {
    int b, wblk;
    xcd_decode(blockIdx.x, 16, b, wblk);
    int off = ((wblk*256 + threadIdx.x) << 2);   // 0..16383 within batch plane
    const float* pb = rp + (size_t)b*16*HW + off;
    float ax=0.f, ay=0.f, az=0.f, aw=0.f;
    #pragma unroll
    for (int c = 0; c < 16; ++c) {
        int gi = b*4 + (c>>3)*2;
        float mu = sr[gi] * (1.f/131072.f);
        float var = sr[gi+1]*(1.f/131072.f) - mu*mu;
        float rs = rsqrtf(var + EPS);
        float ga = gref[c]*rs, bb = bref[c] - mu*ga;
        float wv = wseg[c];
        float4 v = *(const float4*)(pb + (size_t)c*HW);
        ax += wv*mishf(v.x*ga + bb);
        ay += wv*mishf(v.y*ga + bb);
        az += wv*mishf(v.z*ga + bb);
        aw += wv*mishf(v.w*ga + bb);
    }
    *(float4*)(seg + (size_t)b*HW + off) = make_float4(ax,ay,az,aw);
}

// ---------------- K7: bilinear x4 upsample + sigmoid ----------------
__global__ __launch_bounds__(256) void k_up(const float* __restrict__ seg, float* __restrict__ out) {
    int i4 = blockIdx.x * 256 + threadIdx.x;    // 3,145,728 total
    int b = i4 / (512*128);
    int rem = i4 - b*(512*128);
    int y = rem >> 7; int k = rem & 127;
    const float* sp = seg + (size_t)b * HW;
    float fy = fminf(fmaxf(0.25f*y - 0.375f, 0.f), 127.f);
    int y0 = min((int)fy, 126);
    float wy = fy - (float)y0;
    const float* r0 = sp + y0*WW;
    const float* r1 = r0 + WW;
    float res[4];
    #pragma unroll
    for (int j = 0; j < 4; ++j) {
        int x = k*4 + j;
        float fx = fminf(fmaxf(0.25f*x - 0.375f, 0.f), 127.f);
        int x0 = min((int)fx, 126);
        float wx = fx - (float)x0;
        float v0 = r0[x0]*(1.f-wx) + r0[x0+1]*wx;
        float v1 = r1[x0]*(1.f-wx) + r1[x0+1]*wx;
        float v = v0*(1.f-wy) + v1*wy;
        res[j] = 1.f/(1.f + __expf(-v));
    }
    *(float4*)(out + (size_t)i4*4) = make_float4(res[0],res[1],res[2],res[3]);
}

extern "C" void kernel_launch(void* const* d_in, const int* in_sizes, int n_in,
                              void* d_out, int out_size, void* d_ws, size_t ws_size,
                              hipStream_t stream) {
    const float* low  = (const float*)d_in[0];
    const float* high = (const float*)d_in[1];
    const float* Wc0  = (const float*)d_in[2];
    const float* Wc1  = (const float*)d_in[3];
    const float* Wc2  = (const float*)d_in[4];
    const float* gbn  = (const float*)d_in[5];
    const float* bbn  = (const float*)d_in[6];
    const float* Wlow = (const float*)d_in[7];
    const float* glow = (const float*)d_in[8];
    const float* blow = (const float*)d_in[9];
    const float* Wref = (const float*)d_in[10];
    const float* gref = (const float*)d_in[11];
    const float* bref = (const float*)d_in[12];
    const float* Wseg = (const float*)d_in[13];

    float* ws = (float*)d_ws;
    float* A  = ws;                        // in0, later r
    float* Bb = ws + (size_t)SZ;           // high_pre, later ref_pre
    float* C  = ws + 2*(size_t)SZ;         // low_pre
    float* D  = ws + 3*(size_t)SZ;         // seg (48*16384)
    float* ST = D + (size_t)48*HW;         // stats: 480 floats (zeroed each launch)
    float* ZB = ST + 480;                  // 64 zeroed floats: OOB-load redirect target
    float* WTb = ZB + 64;                  // 1152 floats: branch weights [br][ci][kyx][co8]
    float* WTr = WTb + 1152;               // 2304 floats: ref weights [h][ci][kyx][co8]

    hipMemsetAsync(ST, 0, (480 + 64)*sizeof(float), stream);

    k_c0     <<<768,   256, 0, stream>>>(high, Wc0, Wc1, Wc2, Wref, WTb, WTr, A);
    k_branch3<<<1536,  256, 0, stream>>>(A, WTb, ZB, Bb, ST);
    k_low    <<<768,   256, 0, stream>>>(low, Wlow, C, ST + 96);
    k_fuse   <<<12288, 256, 0, stream>>>(Bb, C, gbn, bbn, glow, blow, ST, ST + 96, A);
    k_ref3   <<<1536,  256, 0, stream>>>(A, WTr, ZB, Bb, ST + 288);
    k_seg    <<<768,   256, 0, stream>>>(Bb, gref, bref, Wseg, ST + 288, D);
    k_up     <<<12288, 256, 0, stream>>>(D, (float*)d_out);
}

// Round 4
// 433.806 us; speedup vs baseline: 1.1289x; 1.1289x over previous
//
#include <hip/hip_runtime.h>
#include <math.h>

#define BATCH 48
#define HH 128
#define WW 128
#define HW (128*128)
#define SZ (48*16*HW)          // 12,582,912 floats per 16-ch feature map
#define EPS 1e-5f

// mish(x) = x*tanh(softplus(x)) = x * t(t+2)/(t(t+2)+2), t = e^x  (exact identity)
__device__ __forceinline__ float mishf(float v) {
    float t = __expf(fminf(v, 20.f));      // clamp: for v>20 result == v to fp32 precision
    float u = t * (t + 2.f);
    return v * (u / (u + 2.f));
}

// XCD-affinity decode: linear block L -> (xcd = L&7) owns batches b == xcd (mod 8).
// bpb = blocks per batch (compile-time constant at every call site -> folds to shifts).
__device__ __forceinline__ void xcd_decode(int L, int bpb, int& b, int& w) {
    int xcd = L & 7;
    int j   = L >> 3;
    b = xcd + 8 * (j / bpb);
    w = j - (j / bpb) * bpb;
}

// ---------------- K1: 1x1 conv 32->16 (high_fea -> in0) + weight transposes ----------------
// grid 768 = 48 b * 16 blocks; XCD-sharded by batch.
__global__ __launch_bounds__(256) void k_c0(const float* __restrict__ x,
                                            const float* __restrict__ W,
                                            const float* __restrict__ Wc1,
                                            const float* __restrict__ Wc2,
                                            const float* __restrict__ Wref,
                                            float* __restrict__ WTb,   // 1152 floats
                                            float* __restrict__ WTr,   // 2304 floats
                                            float* __restrict__ out) {
    __shared__ float w[16*32];
    int tid = threadIdx.x;
    for (int i = tid; i < 512; i += 256) w[i] = W[i];
    if (blockIdx.x == 0) {
        for (int i = tid; i < 576; i += 256) {
            int co = i & 7; int t = i >> 3; int kyx = t % 9; int ci = t / 9;
            WTb[(ci*9 + kyx)*8 + co]       = Wc1[(co*8 + ci)*9 + kyx];
            WTb[576 + (ci*9 + kyx)*8 + co] = Wc2[(co*8 + ci)*9 + kyx];
        }
        for (int i = tid; i < 2304; i += 256) {
            int co = i & 7; int t = i >> 3; int kyx = t % 9; int cih = t / 9;  // 0..31
            int ci = cih & 15; int h = cih >> 4;
            WTr[((h*16 + ci)*9 + kyx)*8 + co] = Wref[((h*8 + co)*16 + ci)*9 + kyx];
        }
    }
    __syncthreads();
    int b, wblk;
    xcd_decode(blockIdx.x, 16, b, wblk);
    int off = ((wblk*256 + tid) << 2);       // 1024 px per block, 16 blocks per batch
    const float* xb = x + (size_t)b * 32 * HW + off;
    float acc[16][4];
    #pragma unroll
    for (int c = 0; c < 16; ++c) { acc[c][0]=acc[c][1]=acc[c][2]=acc[c][3]=0.f; }
    #pragma unroll 8
    for (int ci = 0; ci < 32; ++ci) {
        float4 xv = *(const float4*)(xb + (size_t)ci * HW);
        #pragma unroll
        for (int co = 0; co < 16; ++co) {
            float wv = w[co*32 + ci];
            acc[co][0] += wv*xv.x; acc[co][1] += wv*xv.y;
            acc[co][2] += wv*xv.z; acc[co][3] += wv*xv.w;
        }
    }
    float* ob = out + (size_t)b * 16 * HW + off;
    #pragma unroll
    for (int co = 0; co < 16; ++co)
        *(float4*)(ob + (size_t)co * HW) = make_float4(acc[co][0],acc[co][1],acc[co][2],acc[co][3]);
}

// -------- direct-from-global 3x3 conv, 8 px/thread, software-pipelined loads --------
// Tile 128 wide x 8 tall, 128 threads: thread (tx,ty) computes px x=tx*8..tx*8+7, y=y0+ty
// for 8 output channels. Per (ci,ky) group: 4 aligned float4 loads (window tx*8-4..tx*8+11)
// feeding 192 FMAs. 3-buffer pipeline: group g+1's loads issue before group g's FMAs.
template<int D, int NCI>
__device__ __forceinline__ void dconv8(const float* __restrict__ base,   // NCI ch planes
                                       const float* __restrict__ wb,     // NCI*72 [ci][kyx][co8]
                                       const float* __restrict__ zb,     // >=16 zeroed floats
                                       float* __restrict__ obase,        // 8 ch planes
                                       float* __restrict__ statp,        // 2 floats
                                       int y0, int tid) {
    int tx = tid & 15, ty = tid >> 4;      // 16 x 8
    int y  = y0 + ty;
    int xg = tx*8 - 4;                     // leftmost loaded float (mult of 4)
    bool mx0 = (tx > 0);                   // f4 @ xg       (only OOB at tx=0)
    bool mx3 = (tx < 15);                  // f4 @ xg+12    (only OOB at tx=15)
    bool my[3];
    #pragma unroll
    for (int ky = 0; ky < 3; ++ky) my[ky] = ((unsigned)(y + D*(ky-1)) < 128u);

    float acc[8][8];
    #pragma unroll
    for (int c = 0; c < 8; ++c)
        #pragma unroll
        for (int j = 0; j < 8; ++j) acc[c][j] = 0.f;

    float4 A0,A1,A2,A3, B0,B1,B2,B3, C0,C1,C2,C3;

    auto LD = [&](const float* cb, int ky, float4& d0, float4& d1, float4& d2, float4& d3) {
        const float* rp = cb + (y + D*(ky-1))*WW;
        bool m = my[ky];
        d0 = *(const float4*)((m && mx0) ? rp      : zb);
        d1 = *(const float4*)( m         ? rp + 4  : zb);
        d2 = *(const float4*)( m         ? rp + 8  : zb);
        d3 = *(const float4*)((m && mx3) ? rp + 12 : zb);
    };
    auto FMAG = [&](const float* wp, float4 d0, float4 d1, float4 d2, float4 d3) {
        float u[16] = {d0.x,d0.y,d0.z,d0.w, d1.x,d1.y,d1.z,d1.w,
                       d2.x,d2.y,d2.z,d2.w, d3.x,d3.y,d3.z,d3.w};
        #pragma unroll
        for (int kx = 0; kx < 3; ++kx) {
            const float* wq = wp + kx*8;
            float w0 = wq[0], w1 = wq[1], w2 = wq[2], w3 = wq[3];
            float w4 = wq[4], w5 = wq[5], w6 = wq[6], w7 = wq[7];
            #pragma unroll
            for (int j = 0; j < 8; ++j) {
                float xv = u[4 - D + D*kx + j];
                acc[0][j] += w0*xv; acc[1][j] += w1*xv;
                acc[2][j] += w2*xv; acc[3][j] += w3*xv;
                acc[4][j] += w4*xv; acc[5][j] += w5*xv;
                acc[6][j] += w6*xv; acc[7][j] += w7*xv;
            }
        }
    };

    const float* cb = base + xg;
    const float* wp = wb;
    LD(cb, 0, A0,A1,A2,A3);
    #pragma unroll 1
    for (int ci = 0; ci < NCI; ++ci) {
        LD(cb, 1, B0,B1,B2,B3);
        FMAG(wp,      A0,A1,A2,A3);
        LD(cb, 2, C0,C1,C2,C3);
        FMAG(wp + 24, B0,B1,B2,B3);
        if (ci + 1 < NCI) LD(cb + HW, 0, A0,A1,A2,A3);
        FMAG(wp + 48, C0,C1,C2,C3);
        cb += HW; wp += 72;
    }

    // ---- write + GN partial stats ----
    float s = 0.f, q = 0.f;
    float* ob = obase + y*WW + tx*8;
    #pragma unroll
    for (int c = 0; c < 8; ++c) {
        *(float4*)(ob + (size_t)c*HW)     = make_float4(acc[c][0],acc[c][1],acc[c][2],acc[c][3]);
        *(float4*)(ob + (size_t)c*HW + 4) = make_float4(acc[c][4],acc[c][5],acc[c][6],acc[c][7]);
        #pragma unroll
        for (int j = 0; j < 8; ++j) { s += acc[c][j]; q += acc[c][j]*acc[c][j]; }
    }
    #pragma unroll
    for (int o = 32; o > 0; o >>= 1) { s += __shfl_down(s,o); q += __shfl_down(q,o); }
    if ((tid & 63) == 0) { atomicAdd(&statp[0], s); atomicAdd(&statp[1], q); }
}

// ---------------- K2: dual-branch 3x3; flat grid 1536, XCD-sharded ----------------
// per batch: 32 blocks = 2 branch * 16 yblk
__global__ __launch_bounds__(128) void k_branch4(const float* __restrict__ in0,
                                                 const float* __restrict__ WTb,
                                                 const float* __restrict__ zb,
                                                 float* __restrict__ outp,
                                                 float* __restrict__ stat) {
    int b, w;
    xcd_decode(blockIdx.x, 32, b, w);
    int br = w >> 4;
    int y0 = (w & 15) << 3;
    int tid = threadIdx.x;
    if (br == 0) {
        dconv8<1,8>(in0 + (size_t)(b*16    )*HW, WTb,       zb,
                    outp + (size_t)(b*16    )*HW, stat + b*2, y0, tid);
    } else {
        dconv8<2,8>(in0 + (size_t)(b*16 + 8)*HW, WTb + 576, zb,
                    outp + (size_t)(b*16 + 8)*HW, stat + b*2, y0, tid);
    }
}

// ---------------- K3: 1x1 conv 24->16 (low) + GN(groups=2) stats; XCD-sharded ----------------
__global__ __launch_bounds__(256) void k_low(const float* __restrict__ x,
                                             const float* __restrict__ W,
                                             float* __restrict__ outp,
                                             float* __restrict__ stat) {
    __shared__ float w[16*24];
    int tid = threadIdx.x;
    for (int i = tid; i < 384; i += 256) w[i] = W[i];
    __syncthreads();
    int b, wblk;
    xcd_decode(blockIdx.x, 16, b, wblk);
    int off = ((wblk*256 + tid) << 2);
    const float* xb = x + (size_t)b * 24 * HW + off;
    float acc[16][4];
    #pragma unroll
    for (int c = 0; c < 16; ++c) { acc[c][0]=acc[c][1]=acc[c][2]=acc[c][3]=0.f; }
    #pragma unroll 8
    for (int ci = 0; ci < 24; ++ci) {
        float4 xv = *(const float4*)(xb + (size_t)ci * HW);
        #pragma unroll
        for (int co = 0; co < 16; ++co) {
            float wv = w[co*24 + ci];
            acc[co][0] += wv*xv.x; acc[co][1] += wv*xv.y;
            acc[co][2] += wv*xv.z; acc[co][3] += wv*xv.w;
        }
    }
    float* ob = outp + (size_t)b * 16 * HW + off;
    float s0=0.f,q0=0.f,s1=0.f,q1=0.f;
    #pragma unroll
    for (int co = 0; co < 16; ++co) {
        *(float4*)(ob + (size_t)co * HW) = make_float4(acc[co][0],acc[co][1],acc[co][2],acc[co][3]);
        #pragma unroll
        for (int j = 0; j < 4; ++j) {
            if (co < 8) { s0 += acc[co][j]; q0 += acc[co][j]*acc[co][j]; }
            else        { s1 += acc[co][j]; q1 += acc[co][j]*acc[co][j]; }
        }
    }
    #pragma unroll
    for (int o = 32; o > 0; o >>= 1) {
        s0 += __shfl_down(s0,o); q0 += __shfl_down(q0,o);
        s1 += __shfl_down(s1,o); q1 += __shfl_down(q1,o);
    }
    if ((tid & 63) == 0) {
        atomicAdd(&stat[b*4+0], s0); atomicAdd(&stat[b*4+1], q0);
        atomicAdd(&stat[b*4+2], s1); atomicAdd(&stat[b*4+3], q1);
    }
}

// ---------------- K4: GN-apply (high & low) + add + mish; XCD-sharded ----------------
__global__ __launch_bounds__(256) void k_fuse(const float* __restrict__ hp, const float* __restrict__ lp,
                                              const float* __restrict__ gbn, const float* __restrict__ bbn,
                                              const float* __restrict__ glow, const float* __restrict__ blow,
                                              const float* __restrict__ sh, const float* __restrict__ sl,
                                              float* __restrict__ r) {
    int b, wblk;
    xcd_decode(blockIdx.x, 256, b, wblk);
    int idx = wblk*256 + threadIdx.x;        // 0..65535 f4-groups within batch
    int p = b*262144 + (idx << 2);
    int c = idx >> 12;                       // channel 0..15
    float muh = sh[b*2] * (1.f/262144.f);
    float varh = sh[b*2+1]*(1.f/262144.f) - muh*muh;
    float rsh = rsqrtf(varh + EPS);
    int gi = b*4 + (c>>3)*2;
    float mul = sl[gi] * (1.f/131072.f);
    float varl = sl[gi+1]*(1.f/131072.f) - mul*mul;
    float rsl = rsqrtf(varl + EPS);
    float ga = gbn[c]*rsh, bh = bbn[c] - muh*ga;
    float gl = glow[c]*rsl, bl = blow[c] - mul*gl;
    float4 h = *(const float4*)(hp + (size_t)p);
    float4 l = *(const float4*)(lp + (size_t)p);
    float4 o;
    o.x = mishf(h.x*ga + bh + l.x*gl + bl);
    o.y = mishf(h.y*ga + bh + l.y*gl + bl);
    o.z = mishf(h.z*ga + bh + l.z*gl + bl);
    o.w = mishf(h.w*ga + bh + l.w*gl + bl);
    *(float4*)(r + (size_t)p) = o;
}

// ---------------- K5: 3x3 conv 16->16 pad1; flat grid 1536, XCD-sharded ----------------
// per batch: 32 blocks = 2 co-half * 16 yblk
__global__ __launch_bounds__(128) void k_ref4(const float* __restrict__ rin,
                                              const float* __restrict__ WTr,
                                              const float* __restrict__ zb,
                                              float* __restrict__ outp,
                                              float* __restrict__ stat) {
    int b, w;
    xcd_decode(blockIdx.x, 32, b, w);
    int h  = w >> 4;
    int y0 = (w & 15) << 3;
    int tid = threadIdx.x;
    dconv8<1,16>(rin + (size_t)b*16*HW, WTr + h*1152, zb,
                 outp + (size_t)(b*16 + h*8)*HW, stat + b*4 + h*2, y0, tid);
}

// ---------------- K6: GN-apply + mish + 1x1 seg conv 16->1; XCD-sharded ----------------
__global__ __launch_bounds__(256) void k_seg(const float* __restrict__ rp,
                                             const float* __restrict__ gref, const float* __restrict__ bref,
                                             const float* __restrict__ wseg, const float* __restrict__ sr,
                                             float* __restrict__ seg) {
    int b, wblk;
    xcd_decode(blockIdx.x, 16, b, wblk);
    int off = ((wblk*256 + threadIdx.x) << 2);   // 0..16383 within batch plane
    const float* pb = rp + (size_t)b*16*HW + off;
    float ax=0.f, ay=0.f, az=0.f, aw=0.f;
    #pragma unroll
    for (int c = 0; c < 16; ++c) {
        int gi = b*4 + (c>>3)*2;
        float mu = sr[gi] * (1.f/131072.f);
        float var = sr[gi+1]*(1.f/131072.f) - mu*mu;
        float rs = rsqrtf(var + EPS);
        float ga = gref[c]*rs, bb = bref[c] - mu*ga;
        float wv = wseg[c];
        float4 v = *(const float4*)(pb + (size_t)c*HW);
        ax += wv*mishf(v.x*ga + bb);
        ay += wv*mishf(v.y*ga + bb);
        az += wv*mishf(v.z*ga + bb);
        aw += wv*mishf(v.w*ga + bb);
    }
    *(float4*)(seg + (size_t)b*HW + off) = make_float4(ax,ay,az,aw);
}

// ---------------- K7: bilinear x4 upsample + sigmoid ----------------
__global__ __launch_bounds__(256) void k_up(const float* __restrict__ seg, float* __restrict__ out) {
    int i4 = blockIdx.x * 256 + threadIdx.x;    // 3,145,728 total
    int b = i4 / (512*128);
    int rem = i4 - b*(512*128);
    int y = rem >> 7; int k = rem & 127;
    const float* sp = seg + (size_t)b * HW;
    float fy = fminf(fmaxf(0.25f*y - 0.375f, 0.f), 127.f);
    int y0 = min((int)fy, 126);
    float wy = fy - (float)y0;
    const float* r0 = sp + y0*WW;
    const float* r1 = r0 + WW;
    float res[4];
    #pragma unroll
    for (int j = 0; j < 4; ++j) {
        int x = k*4 + j;
        float fx = fminf(fmaxf(0.25f*x - 0.375f, 0.f), 127.f);
        int x0 = min((int)fx, 126);
        float wx = fx - (float)x0;
        float v0 = r0[x0]*(1.f-wx) + r0[x0+1]*wx;
        float v1 = r1[x0]*(1.f-wx) + r1[x0+1]*wx;
        float v = v0*(1.f-wy) + v1*wy;
        res[j] = 1.f/(1.f + __expf(-v));
    }
    *(float4*)(out + (size_t)i4*4) = make_float4(res[0],res[1],res[2],res[3]);
}

extern "C" void kernel_launch(void* const* d_in, const int* in_sizes, int n_in,
                              void* d_out, int out_size, void* d_ws, size_t ws_size,
                              hipStream_t stream) {
    const float* low  = (const float*)d_in[0];
    const float* high = (const float*)d_in[1];
    const float* Wc0  = (const float*)d_in[2];
    const float* Wc1  = (const float*)d_in[3];
    const float* Wc2  = (const float*)d_in[4];
    const float* gbn  = (const float*)d_in[5];
    const float* bbn  = (const float*)d_in[6];
    const float* Wlow = (const float*)d_in[7];
    const float* glow = (const float*)d_in[8];
    const float* blow = (const float*)d_in[9];
    const float* Wref = (const float*)d_in[10];
    const float* gref = (const float*)d_in[11];
    const float* bref = (const float*)d_in[12];
    const float* Wseg = (const float*)d_in[13];

    float* ws = (float*)d_ws;
    float* A  = ws;                        // in0, later r
    float* Bb = ws + (size_t)SZ;           // high_pre, later ref_pre
    float* C  = ws + 2*(size_t)SZ;         // low_pre
    float* D  = ws + 3*(size_t)SZ;         // seg (48*16384)
    float* ST = D + (size_t)48*HW;         // stats: 480 floats (zeroed each launch)
    float* ZB = ST + 480;                  // 64 zeroed floats: OOB-load redirect target
    float* WTb = ZB + 64;                  // 1152 floats: branch weights [br][ci][kyx][co8]
    float* WTr = WTb + 1152;               // 2304 floats: ref weights [h][ci][kyx][co8]

    hipMemsetAsync(ST, 0, (480 + 64)*sizeof(float), stream);

    k_c0     <<<768,   256, 0, stream>>>(high, Wc0, Wc1, Wc2, Wref, WTb, WTr, A);
    k_branch4<<<1536,  128, 0, stream>>>(A, WTb, ZB, Bb, ST);
    k_low    <<<768,   256, 0, stream>>>(low, Wlow, C, ST + 96);
    k_fuse   <<<12288, 256, 0, stream>>>(Bb, C, gbn, bbn, glow, blow, ST, ST + 96, A);
    k_ref4   <<<1536,  128, 0, stream>>>(A, WTr, ZB, Bb, ST + 288);
    k_seg    <<<768,   256, 0, stream>>>(Bb, gref, bref, Wseg, ST + 288, D);
    k_up     <<<12288, 256, 0, stream>>>(D, (float*)d_out);
}

// Round 5
// 417.002 us; speedup vs baseline: 1.1744x; 1.0403x over previous
//
#include <hip/hip_runtime.h>
#include <hip/hip_fp16.h>
#include <math.h>

#define BATCH 48
#define HH 128
#define WW 128
#define HW (128*128)
#define SZ (48*16*HW)          // element count of a 16-ch feature map (fp32-slot sized regions)
#define EPS 1e-5f

// ---- fp16 vector helpers (storage fp16, compute fp32) ----
struct __align__(8)  h4 { __half2 a, b; };
struct __align__(16) h8 { __half2 a, b, c, d; };

__device__ __forceinline__ float4 h4f(h4 v) {
    float2 f0 = __half22float2(v.a), f1 = __half22float2(v.b);
    return make_float4(f0.x, f0.y, f1.x, f1.y);
}
__device__ __forceinline__ h4 f4h(float4 v) {
    h4 r; r.a = __floats2half2_rn(v.x, v.y); r.b = __floats2half2_rn(v.z, v.w); return r;
}

// mish(x) = x*tanh(softplus(x)) = x * t(t+2)/(t(t+2)+2), t = e^x  (exact identity)
__device__ __forceinline__ float mishf(float v) {
    float t = __expf(fminf(v, 20.f));
    float u = t * (t + 2.f);
    return v * (u / (u + 2.f));
}

// XCD-affinity decode: linear block L -> (xcd = L&7) owns batches b == xcd (mod 8).
__device__ __forceinline__ void xcd_decode(int L, int bpb, int& b, int& w) {
    int xcd = L & 7;
    int j   = L >> 3;
    b = xcd + 8 * (j / bpb);
    w = j - (j / bpb) * bpb;
}

// ---------------- K1: 1x1 conv 32->16 (high_fea -> in0 fp16) + weight transposes ----------------
// grid 768 = 48 b * 16 blocks; XCD-sharded by batch.
__global__ __launch_bounds__(256) void k_c0(const float* __restrict__ x,
                                            const float* __restrict__ W,
                                            const float* __restrict__ Wc1,
                                            const float* __restrict__ Wc2,
                                            const float* __restrict__ Wref,
                                            float* __restrict__ WTb,   // 1152 floats
                                            float* __restrict__ WTr,   // 2304 floats
                                            __half* __restrict__ out) {
    __shared__ float w[16*32];
    int tid = threadIdx.x;
    for (int i = tid; i < 512; i += 256) w[i] = W[i];
    if (blockIdx.x == 0) {
        for (int i = tid; i < 576; i += 256) {
            int co = i & 7; int t = i >> 3; int kyx = t % 9; int ci = t / 9;
            WTb[(ci*9 + kyx)*8 + co]       = Wc1[(co*8 + ci)*9 + kyx];
            WTb[576 + (ci*9 + kyx)*8 + co] = Wc2[(co*8 + ci)*9 + kyx];
        }
        for (int i = tid; i < 2304; i += 256) {
            int co = i & 7; int t = i >> 3; int kyx = t % 9; int cih = t / 9;  // 0..31
            int ci = cih & 15; int h = cih >> 4;
            WTr[((h*16 + ci)*9 + kyx)*8 + co] = Wref[((h*8 + co)*16 + ci)*9 + kyx];
        }
    }
    __syncthreads();
    int b, wblk;
    xcd_decode(blockIdx.x, 16, b, wblk);
    int off = ((wblk*256 + tid) << 2);       // 4 px per thread
    const float* xb = x + (size_t)b * 32 * HW + off;
    float acc[16][4];
    #pragma unroll
    for (int c = 0; c < 16; ++c) { acc[c][0]=acc[c][1]=acc[c][2]=acc[c][3]=0.f; }
    #pragma unroll 8
    for (int ci = 0; ci < 32; ++ci) {
        float4 xv = *(const float4*)(xb + (size_t)ci * HW);
        #pragma unroll
        for (int co = 0; co < 16; ++co) {
            float wv = w[co*32 + ci];
            acc[co][0] += wv*xv.x; acc[co][1] += wv*xv.y;
            acc[co][2] += wv*xv.z; acc[co][3] += wv*xv.w;
        }
    }
    __half* ob = out + (size_t)b * 16 * HW + off;
    #pragma unroll
    for (int co = 0; co < 16; ++co)
        *(h4*)(ob + (size_t)co * HW) = f4h(make_float4(acc[co][0],acc[co][1],acc[co][2],acc[co][3]));
}

// -------- direct-from-global 3x3 conv, fp16 in/out, 8 px/thread, software-pipelined --------
// Tile 128 wide x 8 tall, 128 threads. Per (ci,ky): 4x 8-byte h4 loads feeding 192 fp32 FMAs.
// 3-buffer pipeline: group g+1's loads issue before group g's FMAs.
template<int D, int NCI>
__device__ __forceinline__ void dconv8(const __half* __restrict__ base,  // NCI ch planes
                                       const float* __restrict__ wb,     // NCI*72 [ci][kyx][co8]
                                       const __half* __restrict__ zh,    // >=16 zeroed halfs
                                       __half* __restrict__ obase,       // 8 ch planes
                                       float* __restrict__ statp,        // 2 floats
                                       int y0, int tid) {
    int tx = tid & 15, ty = tid >> 4;      // 16 x 8
    int y  = y0 + ty;
    int xg = tx*8 - 4;                     // leftmost loaded element (mult of 4)
    bool mx0 = (tx > 0);                   // h4 @ xg
    bool mx3 = (tx < 15);                  // h4 @ xg+12
    bool my[3];
    #pragma unroll
    for (int ky = 0; ky < 3; ++ky) my[ky] = ((unsigned)(y + D*(ky-1)) < 128u);

    float acc[8][8];
    #pragma unroll
    for (int c = 0; c < 8; ++c)
        #pragma unroll
        for (int j = 0; j < 8; ++j) acc[c][j] = 0.f;

    h4 A0,A1,A2,A3, B0,B1,B2,B3, C0,C1,C2,C3;

    auto LD = [&](const __half* cb, int ky, h4& d0, h4& d1, h4& d2, h4& d3) {
        const __half* rp = cb + (y + D*(ky-1))*WW;
        bool m = my[ky];
        d0 = *(const h4*)((m && mx0) ? rp      : zh);
        d1 = *(const h4*)( m         ? rp + 4  : zh);
        d2 = *(const h4*)( m         ? rp + 8  : zh);
        d3 = *(const h4*)((m && mx3) ? rp + 12 : zh);
    };
    auto FMAG = [&](const float* wp, h4 d0, h4 d1, h4 d2, h4 d3) {
        float4 f0 = h4f(d0), f1 = h4f(d1), f2 = h4f(d2), f3 = h4f(d3);
        float u[16] = {f0.x,f0.y,f0.z,f0.w, f1.x,f1.y,f1.z,f1.w,
                       f2.x,f2.y,f2.z,f2.w, f3.x,f3.y,f3.z,f3.w};
        #pragma unroll
        for (int kx = 0; kx < 3; ++kx) {
            const float* wq = wp + kx*8;
            float w0 = wq[0], w1 = wq[1], w2 = wq[2], w3 = wq[3];
            float w4 = wq[4], w5 = wq[5], w6 = wq[6], w7 = wq[7];
            #pragma unroll
            for (int j = 0; j < 8; ++j) {
                float xv = u[4 - D + D*kx + j];
                acc[0][j] += w0*xv; acc[1][j] += w1*xv;
                acc[2][j] += w2*xv; acc[3][j] += w3*xv;
                acc[4][j] += w4*xv; acc[5][j] += w5*xv;
                acc[6][j] += w6*xv; acc[7][j] += w7*xv;
            }
        }
    };

    const __half* cb = base + xg;
    const float* wp = wb;
    LD(cb, 0, A0,A1,A2,A3);
    #pragma unroll 1
    for (int ci = 0; ci < NCI; ++ci) {
        LD(cb, 1, B0,B1,B2,B3);
        FMAG(wp,      A0,A1,A2,A3);
        LD(cb, 2, C0,C1,C2,C3);
        FMAG(wp + 24, B0,B1,B2,B3);
        if (ci + 1 < NCI) LD(cb + HW, 0, A0,A1,A2,A3);
        FMAG(wp + 48, C0,C1,C2,C3);
        cb += HW; wp += 72;
    }

    // ---- write (fp16) + GN partial stats (fp32) ----
    float s = 0.f, q = 0.f;
    __half* ob = obase + y*WW + tx*8;
    #pragma unroll
    for (int c = 0; c < 8; ++c) {
        h8 o;
        o.a = __floats2half2_rn(acc[c][0], acc[c][1]);
        o.b = __floats2half2_rn(acc[c][2], acc[c][3]);
        o.c = __floats2half2_rn(acc[c][4], acc[c][5]);
        o.d = __floats2half2_rn(acc[c][6], acc[c][7]);
        *(h8*)(ob + (size_t)c*HW) = o;
        #pragma unroll
        for (int j = 0; j < 8; ++j) { s += acc[c][j]; q += acc[c][j]*acc[c][j]; }
    }
    #pragma unroll
    for (int o = 32; o > 0; o >>= 1) { s += __shfl_down(s,o); q += __shfl_down(q,o); }
    if ((tid & 63) == 0) { atomicAdd(&statp[0], s); atomicAdd(&statp[1], q); }
}

// ---------------- K2: dual-branch 3x3; flat grid 1536, XCD-sharded ----------------
__global__ __launch_bounds__(128) void k_branch5(const __half* __restrict__ in0,
                                                 const float* __restrict__ WTb,
                                                 const __half* __restrict__ zh,
                                                 __half* __restrict__ outp,
                                                 float* __restrict__ stat) {
    int b, w;
    xcd_decode(blockIdx.x, 32, b, w);
    int br = w >> 4;
    int y0 = (w & 15) << 3;
    int tid = threadIdx.x;
    if (br == 0) {
        dconv8<1,8>(in0 + (size_t)(b*16    )*HW, WTb,       zh,
                    outp + (size_t)(b*16    )*HW, stat + b*2, y0, tid);
    } else {
        dconv8<2,8>(in0 + (size_t)(b*16 + 8)*HW, WTb + 576, zh,
                    outp + (size_t)(b*16 + 8)*HW, stat + b*2, y0, tid);
    }
}

// ---------------- K3: 1x1 conv 24->16 (low, fp16 out) + GN(groups=2) stats ----------------
__global__ __launch_bounds__(256) void k_low(const float* __restrict__ x,
                                             const float* __restrict__ W,
                                             __half* __restrict__ outp,
                                             float* __restrict__ stat) {
    __shared__ float w[16*24];
    int tid = threadIdx.x;
    for (int i = tid; i < 384; i += 256) w[i] = W[i];
    __syncthreads();
    int b, wblk;
    xcd_decode(blockIdx.x, 16, b, wblk);
    int off = ((wblk*256 + tid) << 2);
    const float* xb = x + (size_t)b * 24 * HW + off;
    float acc[16][4];
    #pragma unroll
    for (int c = 0; c < 16; ++c) { acc[c][0]=acc[c][1]=acc[c][2]=acc[c][3]=0.f; }
    #pragma unroll 8
    for (int ci = 0; ci < 24; ++ci) {
        float4 xv = *(const float4*)(xb + (size_t)ci * HW);
        #pragma unroll
        for (int co = 0; co < 16; ++co) {
            float wv = w[co*24 + ci];
            acc[co][0] += wv*xv.x; acc[co][1] += wv*xv.y;
            acc[co][2] += wv*xv.z; acc[co][3] += wv*xv.w;
        }
    }
    __half* ob = outp + (size_t)b * 16 * HW + off;
    float s0=0.f,q0=0.f,s1=0.f,q1=0.f;
    #pragma unroll
    for (int co = 0; co < 16; ++co) {
        *(h4*)(ob + (size_t)co * HW) = f4h(make_float4(acc[co][0],acc[co][1],acc[co][2],acc[co][3]));
        #pragma unroll
        for (int j = 0; j < 4; ++j) {
            if (co < 8) { s0 += acc[co][j]; q0 += acc[co][j]*acc[co][j]; }
            else        { s1 += acc[co][j]; q1 += acc[co][j]*acc[co][j]; }
        }
    }
    #pragma unroll
    for (int o = 32; o > 0; o >>= 1) {
        s0 += __shfl_down(s0,o); q0 += __shfl_down(q0,o);
        s1 += __shfl_down(s1,o); q1 += __shfl_down(q1,o);
    }
    if ((tid & 63) == 0) {
        atomicAdd(&stat[b*4+0], s0); atomicAdd(&stat[b*4+1], q0);
        atomicAdd(&stat[b*4+2], s1); atomicAdd(&stat[b*4+3], q1);
    }
}

// ---------------- K4: GN-apply (high & low) + add + mish; 8 px/thread, fp16 ----------------
// grid 6144 = 48 b * 128 blocks (each 2048 px of the 262144-px batch slab)
__global__ __launch_bounds__(256) void k_fuse(const __half* __restrict__ hp, const __half* __restrict__ lp,
                                              const float* __restrict__ gbn, const float* __restrict__ bbn,
                                              const float* __restrict__ glow, const float* __restrict__ blow,
                                              const float* __restrict__ sh, const float* __restrict__ sl,
                                              __half* __restrict__ r) {
    int b, wblk;
    xcd_decode(blockIdx.x, 128, b, wblk);
    int idx = wblk*256 + threadIdx.x;        // 0..32767 h8-groups within batch
    int p = b*262144 + (idx << 3);
    int c = idx >> 11;                       // channel 0..15
    float muh = sh[b*2] * (1.f/262144.f);
    float varh = sh[b*2+1]*(1.f/262144.f) - muh*muh;
    float rsh = rsqrtf(varh + EPS);
    int gi = b*4 + (c>>3)*2;
    float mul = sl[gi] * (1.f/131072.f);
    float varl = sl[gi+1]*(1.f/131072.f) - mul*mul;
    float rsl = rsqrtf(varl + EPS);
    float ga = gbn[c]*rsh, bh = bbn[c] - muh*ga;
    float gl = glow[c]*rsl, bl = blow[c] - mul*gl;
    h8 hv = *(const h8*)(hp + (size_t)p);
    h8 lv = *(const h8*)(lp + (size_t)p);
    float2 h01 = __half22float2(hv.a), h23 = __half22float2(hv.b),
           h45 = __half22float2(hv.c), h67 = __half22float2(hv.d);
    float2 l01 = __half22float2(lv.a), l23 = __half22float2(lv.b),
           l45 = __half22float2(lv.c), l67 = __half22float2(lv.d);
    float o0 = mishf(h01.x*ga + bh + l01.x*gl + bl);
    float o1 = mishf(h01.y*ga + bh + l01.y*gl + bl);
    float o2 = mishf(h23.x*ga + bh + l23.x*gl + bl);
    float o3 = mishf(h23.y*ga + bh + l23.y*gl + bl);
    float o4 = mishf(h45.x*ga + bh + l45.x*gl + bl);
    float o5 = mishf(h45.y*ga + bh + l45.y*gl + bl);
    float o6 = mishf(h67.x*ga + bh + l67.x*gl + bl);
    float o7 = mishf(h67.y*ga + bh + l67.y*gl + bl);
    h8 ov;
    ov.a = __floats2half2_rn(o0,o1); ov.b = __floats2half2_rn(o2,o3);
    ov.c = __floats2half2_rn(o4,o5); ov.d = __floats2half2_rn(o6,o7);
    *(h8*)(r + (size_t)p) = ov;
}

// ---------------- K5: 3x3 conv 16->16 pad1; flat grid 1536, XCD-sharded ----------------
__global__ __launch_bounds__(128) void k_ref5(const __half* __restrict__ rin,
                                              const float* __restrict__ WTr,
                                              const __half* __restrict__ zh,
                                              __half* __restrict__ outp,
                                              float* __restrict__ stat) {
    int b, w;
    xcd_decode(blockIdx.x, 32, b, w);
    int h  = w >> 4;
    int y0 = (w & 15) << 3;
    int tid = threadIdx.x;
    dconv8<1,16>(rin + (size_t)b*16*HW, WTr + h*1152, zh,
                 outp + (size_t)(b*16 + h*8)*HW, stat + b*4 + h*2, y0, tid);
}

// ---------------- K6: GN-apply + mish + 1x1 seg conv 16->1; 8 px/thread, fp16 ----------------
// grid 384 = 48 b * 8 blocks
__global__ __launch_bounds__(256) void k_seg(const __half* __restrict__ rp,
                                             const float* __restrict__ gref, const float* __restrict__ bref,
                                             const float* __restrict__ wseg, const float* __restrict__ sr,
                                             __half* __restrict__ seg) {
    int b, wblk;
    xcd_decode(blockIdx.x, 8, b, wblk);
    int off = ((wblk*256 + threadIdx.x) << 3);   // 0..16376 within batch plane
    const __half* pb = rp + (size_t)b*16*HW + off;
    float a0=0,a1=0,a2=0,a3=0,a4=0,a5=0,a6=0,a7=0;
    #pragma unroll
    for (int c = 0; c < 16; ++c) {
        int gi = b*4 + (c>>3)*2;
        float mu = sr[gi] * (1.f/131072.f);
        float var = sr[gi+1]*(1.f/131072.f) - mu*mu;
        float rs = rsqrtf(var + EPS);
        float ga = gref[c]*rs, bb = bref[c] - mu*ga;
        float wv = wseg[c];
        h8 v = *(const h8*)(pb + (size_t)c*HW);
        float2 v01 = __half22float2(v.a), v23 = __half22float2(v.b),
               v45 = __half22float2(v.c), v67 = __half22float2(v.d);
        a0 += wv*mishf(v01.x*ga + bb); a1 += wv*mishf(v01.y*ga + bb);
        a2 += wv*mishf(v23.x*ga + bb); a3 += wv*mishf(v23.y*ga + bb);
        a4 += wv*mishf(v45.x*ga + bb); a5 += wv*mishf(v45.y*ga + bb);
        a6 += wv*mishf(v67.x*ga + bb); a7 += wv*mishf(v67.y*ga + bb);
    }
    h8 ov;
    ov.a = __floats2half2_rn(a0,a1); ov.b = __floats2half2_rn(a2,a3);
    ov.c = __floats2half2_rn(a4,a5); ov.d = __floats2half2_rn(a6,a7);
    *(h8*)(seg + (size_t)b*HW + off) = ov;
}

// ---------------- K7: bilinear x4 upsample + sigmoid (seg fp16 -> out fp32) ----------------
__global__ __launch_bounds__(256) void k_up(const __half* __restrict__ seg, float* __restrict__ out) {
    int i4 = blockIdx.x * 256 + threadIdx.x;    // 3,145,728 total
    int b = i4 / (512*128);
    int rem = i4 - b*(512*128);
    int y = rem >> 7; int k = rem & 127;
    const __half* sp = seg + (size_t)b * HW;
    float fy = fminf(fmaxf(0.25f*y - 0.375f, 0.f), 127.f);
    int y0 = min((int)fy, 126);
    float wy = fy - (float)y0;
    const __half* r0 = sp + y0*WW;
    const __half* r1 = r0 + WW;
    float res[4];
    #pragma unroll
    for (int j = 0; j < 4; ++j) {
        int x = k*4 + j;
        float fx = fminf(fmaxf(0.25f*x - 0.375f, 0.f), 127.f);
        int x0 = min((int)fx, 126);
        float wx = fx - (float)x0;
        float v0 = __half2float(r0[x0])*(1.f-wx) + __half2float(r0[x0+1])*wx;
        float v1 = __half2float(r1[x0])*(1.f-wx) + __half2float(r1[x0+1])*wx;
        float v = v0*(1.f-wy) + v1*wy;
        res[j] = 1.f/(1.f + __expf(-v));
    }
    *(float4*)(out + (size_t)i4*4) = make_float4(res[0],res[1],res[2],res[3]);
}

extern "C" void kernel_launch(void* const* d_in, const int* in_sizes, int n_in,
                              void* d_out, int out_size, void* d_ws, size_t ws_size,
                              hipStream_t stream) {
    const float* low  = (const float*)d_in[0];
    const float* high = (const float*)d_in[1];
    const float* Wc0  = (const float*)d_in[2];
    const float* Wc1  = (const float*)d_in[3];
    const float* Wc2  = (const float*)d_in[4];
    const float* gbn  = (const float*)d_in[5];
    const float* bbn  = (const float*)d_in[6];
    const float* Wlow = (const float*)d_in[7];
    const float* glow = (const float*)d_in[8];
    const float* blow = (const float*)d_in[9];
    const float* Wref = (const float*)d_in[10];
    const float* gref = (const float*)d_in[11];
    const float* bref = (const float*)d_in[12];
    const float* Wseg = (const float*)d_in[13];

    float* ws = (float*)d_ws;
    // fp16 tensors live in fp32-sized slots (half the bytes used; layout kept simple)
    __half* A  = (__half*)ws;                        // in0, later r
    __half* Bb = (__half*)(ws + (size_t)SZ);         // high_pre, later ref_pre
    __half* C  = (__half*)(ws + 2*(size_t)SZ);       // low_pre
    __half* D  = (__half*)(ws + 3*(size_t)SZ);       // seg (48*16384 halfs)
    float* ST = ws + 3*(size_t)SZ + (size_t)48*HW;   // stats: 480 floats (zeroed each launch)
    float* ZB = ST + 480;                            // 64 zeroed floats: OOB-load redirect target
    float* WTb = ZB + 64;                            // 1152 floats
    float* WTr = WTb + 1152;                         // 2304 floats

    hipMemsetAsync(ST, 0, (480 + 64)*sizeof(float), stream);

    k_c0     <<<768,   256, 0, stream>>>(high, Wc0, Wc1, Wc2, Wref, WTb, WTr, A);
    k_branch5<<<1536,  128, 0, stream>>>(A, WTb, (const __half*)ZB, Bb, ST);
    k_low    <<<768,   256, 0, stream>>>(low, Wlow, C, ST + 96);
    k_fuse   <<<6144,  256, 0, stream>>>(Bb, C, gbn, bbn, glow, blow, ST, ST + 96, A);
    k_ref5   <<<1536,  128, 0, stream>>>(A, WTr, (const __half*)ZB, Bb, ST + 288);
    k_seg    <<<384,   256, 0, stream>>>(Bb, gref, bref, Wseg, ST + 288, D);
    k_up     <<<12288, 256, 0, stream>>>(D, (float*)d_out);
}